// Round 5
// baseline (152.014 us; speedup 1.0000x reference)
//
#include <hip/hip_runtime.h>
#include <hip/hip_bf16.h>
#include <math.h>

#define NB 512
#define NT 256
#define NC 384
#define NH 64

typedef __bf16 bf16x8 __attribute__((ext_vector_type(8)));
typedef unsigned short u16x8 __attribute__((ext_vector_type(8)));
typedef unsigned short u16x4 __attribute__((ext_vector_type(4)));
typedef unsigned int   u32x4 __attribute__((ext_vector_type(4)));
typedef float f32x4 __attribute__((ext_vector_type(4)));

__device__ __forceinline__ unsigned short f2bf(float f) {
    union { float f; unsigned u; } v; v.f = f;
    unsigned r = v.u + 0x7FFFu + ((v.u >> 16) & 1u);   // round-to-nearest-even
    return (unsigned short)(r >> 16);
}

__device__ __forceinline__ f32x4 mfma16(bf16x8 a, bf16x8 b, f32x4 c) {
    return __builtin_amdgcn_mfma_f32_16x16x32_bf16(a, b, c, 0, 0, 0);
}

// ============ kernel 1: W -> Wf (bf16, MFMA B-fragment packed) =================
// Wf element e = ((n*12+kk)*64 + l)*8 + j  holds  W_m[c=kk*32+8g+j][h=(n&3)*16+col]
__global__ void prep_w(const float* __restrict__ Wq, const float* __restrict__ Wk,
                       const float* __restrict__ Wv, unsigned short* __restrict__ Wf) {
    const int e = blockIdx.x * 256 + threadIdx.x;   // 0..73727
    const int j  = e & 7;
    const int l  = (e >> 3) & 63;
    const int fi = e >> 9;                          // 0..143
    const int kk = fi % 12;
    const int n  = fi / 12;
    const int g = l >> 4, col = l & 15;
    const int c = kk * 32 + g * 8 + j;
    const int h = (n & 3) * 16 + col;
    const float* W = (n < 4) ? Wq : (n < 8 ? Wk : Wv);
    Wf[e] = f2bf(W[c * 64 + h]);
}

// ============ kernel 2: QKV projection, wave-persistent W ======================
// 512 blocks x 256 thr; each block processes 4 x 64-row groups. Wave w holds
// B-frags for n in {3w..3w+2} in registers for the whole kernel (36 frags).
#define XS_LD   392
#define RPQK_OFF 25088            // shorts; [64][136]
#define RPQK_LD 136
#define RPV_OFF (25088 + 8704)    // shorts; [64][72] (V transposed)
#define RPV_LD  72
#define PSMEM   (25088 + 8704 + 4608)   // 38400 shorts = 76,800 B

__global__ __launch_bounds__(256, 2) void proj_qkv(
    const float* __restrict__ x, const unsigned short* __restrict__ Wf,
    unsigned short* __restrict__ Qg, unsigned short* __restrict__ Kg,
    unsigned short* __restrict__ VTg)
{
    __shared__ __align__(16) unsigned short SM[PSMEM];

    const int tid = threadIdx.x;
    const int w = tid >> 6, lane = tid & 63, g = lane >> 4, col = lane & 15;
    const int n0 = 3 * w;

    // ---- persistent B-frags: wave w owns n = 3w .. 3w+2 (one full Wf read) ----
    bf16x8 Bw[3][12];
    #pragma unroll
    for (int n3 = 0; n3 < 3; ++n3)
        #pragma unroll
        for (int kk = 0; kk < 12; ++kk)
            Bw[n3][kk] = *reinterpret_cast<const bf16x8*>(
                Wf + ((size_t)((n0 + n3) * 12 + kk) * 64 + lane) * 8);

    for (int it = 0; it < 4; ++it) {
        const int row0 = (blockIdx.x * 4 + it) * 64;

        // ---- stage x tile (coalesced float4 stream -> bf16 LDS) ----
        const float* xbase = x + (size_t)row0 * NC;
        #pragma unroll
        for (int k = 0; k < 24; ++k) {
            const int idx = k * 1024 + tid * 4;
            const int row = idx / 384;
            const int c = idx - row * 384;
            const float4 f = *reinterpret_cast<const float4*>(xbase + idx);
            u16x4 u;
            u[0] = f2bf(f.x); u[1] = f2bf(f.y); u[2] = f2bf(f.z); u[3] = f2bf(f.w);
            *reinterpret_cast<u16x4*>(&SM[row * XS_LD + c]) = u;
        }
        __syncthreads();

        // ---- compute: 4 row-tiles x 3 n-tiles per wave, all-register operands ----
        #pragma unroll
        for (int rt = 0; rt < 4; ++rt) {
            f32x4 acc[3];
            acc[0] = (f32x4){0.f,0.f,0.f,0.f};
            acc[1] = (f32x4){0.f,0.f,0.f,0.f};
            acc[2] = (f32x4){0.f,0.f,0.f,0.f};
            #pragma unroll
            for (int half = 0; half < 2; ++half) {
                bf16x8 A[6];
                #pragma unroll
                for (int k6 = 0; k6 < 6; ++k6)
                    A[k6] = *reinterpret_cast<const bf16x8*>(
                        &SM[(rt * 16 + col) * XS_LD + (half * 6 + k6) * 32 + g * 8]);
                #pragma unroll
                for (int k6 = 0; k6 < 6; ++k6)
                    #pragma unroll
                    for (int n3 = 0; n3 < 3; ++n3)
                        acc[n3] = mfma16(A[k6], Bw[n3][half * 6 + k6], acc[n3]);
            }
            // repack into LDS (Q/K rows; V transposed)
            #pragma unroll
            for (int n3 = 0; n3 < 3; ++n3) {
                const int n = n0 + n3;
                #pragma unroll
                for (int r = 0; r < 4; ++r) {
                    const unsigned short v = f2bf(acc[n3][r]);
                    const int row = rt * 16 + g * 4 + r;
                    if (n < 8) SM[RPQK_OFF + row * RPQK_LD + n * 16 + col] = v;
                    else       SM[RPV_OFF + ((n - 8) * 16 + col) * RPV_LD + row] = v;
                }
            }
        }
        __syncthreads();

        // ---- coalesced stores ----
        const int rrow = tid >> 2, seg = tid & 3;
        const size_t gt = (size_t)(row0 + rrow);
        const int b = row0 >> 8, t0 = row0 & 255;
        #pragma unroll
        for (int hseg = 0; hseg < 2; ++hseg) {
            const int o = seg * 16 + hseg * 8;
            *reinterpret_cast<u16x8*>(Qg + gt * 64 + o) =
                *reinterpret_cast<const u16x8*>(&SM[RPQK_OFF + rrow * RPQK_LD + o]);
            *reinterpret_cast<u16x8*>(Kg + gt * 64 + o) =
                *reinterpret_cast<const u16x8*>(&SM[RPQK_OFF + rrow * RPQK_LD + 64 + o]);
            *reinterpret_cast<u16x8*>(VTg + ((size_t)(b * 64 + rrow)) * 256 + t0 + o) =
                *reinterpret_cast<const u16x8*>(&SM[RPV_OFF + rrow * RPV_LD + o]);
        }
        __syncthreads();
    }
}

// ============ kernel 3: attention, swapped-QK^T, 1 barrier =====================
#define ALDK   72
#define AOFF_VT 18432
#define ALDVT  264
#define ASMEM  (18432 + 64 * 264)    // 35328 shorts = 70656 B

__global__ __launch_bounds__(512, 2) void attn(
    const unsigned short* __restrict__ Qg, const unsigned short* __restrict__ Kg,
    const unsigned short* __restrict__ VTg, float* __restrict__ out)
{
    __shared__ __align__(16) unsigned short SM[ASMEM];

    const int b = blockIdx.x, tid = threadIdx.x;
    const int w = tid >> 6, lane = tid & 63, g = lane >> 4, col = lane & 15;

    // ---- stage K rows (coalesced) ----
    #pragma unroll
    for (int it = 0; it < 4; ++it) {
        const int i = it * 512 + tid;
        const int tr = i >> 3, cg = i & 7;
        *reinterpret_cast<u16x8*>(&SM[tr * ALDK + cg * 8]) =
            *reinterpret_cast<const u16x8*>(Kg + ((size_t)b * 256 + tr) * 64 + cg * 8);
    }
    // ---- stage VT rows (coalesced; already transposed by proj) ----
    #pragma unroll
    for (int it = 0; it < 4; ++it) {
        const int i = it * 512 + tid;
        const int hr = i >> 5, seg = i & 31;
        *reinterpret_cast<u16x8*>(&SM[AOFF_VT + hr * ALDVT + seg * 8]) =
            *reinterpret_cast<const u16x8*>(VTg + ((size_t)b * 64 + hr) * 256 + seg * 8);
    }
    __syncthreads();   // the only barrier

    const int hi_half = (lane >> 5) & 1;
    const int srcA = ((lane >> 4) & 1) * 32 + col;
    const int srcB = srcA + 16;

    #pragma unroll
    for (int pass = 0; pass < 2; ++pass) {
        const int MT = pass ? (15 - w) : w;          // balanced causal pairing

        // Q B-frags (16B/lane from L2-hot Qg)
        bf16x8 qb[2];
        #pragma unroll
        for (int kk = 0; kk < 2; ++kk)
            qb[kk] = *reinterpret_cast<const bf16x8*>(
                Qg + ((size_t)b * 256 + MT * 16 + col) * 64 + kk * 32 + g * 8);

        // scores S^T: lane holds S[s=nt*16+4g+r][t=MT*16+col]
        f32x4 sc[16];
        #pragma unroll
        for (int nt = 0; nt < 16; ++nt) {
            if (nt <= MT) {
                f32x4 a = {0.f, 0.f, 0.f, 0.f};
                const bf16x8 ka0 = *reinterpret_cast<const bf16x8*>(
                    &SM[(nt * 16 + col) * ALDK + g * 8]);
                const bf16x8 ka1 = *reinterpret_cast<const bf16x8*>(
                    &SM[(nt * 16 + col) * ALDK + 32 + g * 8]);
                a = mfma16(ka0, qb[0], a);
                a = mfma16(ka1, qb[1], a);
                sc[nt] = a;
            }
        }

        // softmax over s for row t=col; reduce across g with 2 shuffles
        float m = -INFINITY;
        #pragma unroll
        for (int nt = 0; nt < 16; ++nt) {
            if (nt <= MT) {
                #pragma unroll
                for (int r = 0; r < 4; ++r) {
                    float v = sc[nt][r] * 0.125f;
                    if (nt == MT && (4 * g + r) > col) v = -INFINITY;   // causal
                    sc[nt][r] = v;
                    m = fmaxf(m, v);
                }
            }
        }
        m = fmaxf(m, __shfl_xor(m, 16));
        m = fmaxf(m, __shfl_xor(m, 32));
        float s = 0.f;
        #pragma unroll
        for (int nt = 0; nt < 16; ++nt) {
            if (nt <= MT) {
                #pragma unroll
                for (int r = 0; r < 4; ++r) {
                    const float p = __expf(sc[nt][r] - m);
                    sc[nt][r] = p;
                    s += p;
                }
            }
        }
        s += __shfl_xor(s, 16);
        s += __shfl_xor(s, 32);
        const float inv = 1.0f / s;

        // normalized P -> bf16 pairs (per nt: r0|r1, r2|r3)
        unsigned P4lo[16], P4hi[16];
        #pragma unroll
        for (int nt = 0; nt < 16; ++nt) {
            if (nt <= MT) {
                P4lo[nt] = (unsigned)f2bf(sc[nt][0] * inv) |
                           ((unsigned)f2bf(sc[nt][1] * inv) << 16);
                P4hi[nt] = (unsigned)f2bf(sc[nt][2] * inv) |
                           ((unsigned)f2bf(sc[nt][3] * inv) << 16);
            } else { P4lo[nt] = 0u; P4hi[nt] = 0u; }
        }

        // PV: build A-frags via shuffles (no LDS), accumulate O
        f32x4 oacc[4];
        #pragma unroll
        for (int n = 0; n < 4; ++n) oacc[n] = (f32x4){0.f, 0.f, 0.f, 0.f};
        #pragma unroll
        for (int c = 0; c < 8; ++c) {
            if (c <= (MT >> 1)) {
                const unsigned a0 = __shfl(P4lo[2 * c],     srcA, 64);
                const unsigned a1 = __shfl(P4lo[2 * c + 1], srcA, 64);
                const unsigned b0 = __shfl(P4hi[2 * c],     srcA, 64);
                const unsigned b1 = __shfl(P4hi[2 * c + 1], srcA, 64);
                const unsigned c0 = __shfl(P4lo[2 * c],     srcB, 64);
                const unsigned c1 = __shfl(P4lo[2 * c + 1], srcB, 64);
                const unsigned d0 = __shfl(P4hi[2 * c],     srcB, 64);
                const unsigned d1 = __shfl(P4hi[2 * c + 1], srcB, 64);
                u32x4 wv;
                wv[0] = hi_half ? a1 : a0;
                wv[1] = hi_half ? b1 : b0;
                wv[2] = hi_half ? c1 : c0;
                wv[3] = hi_half ? d1 : d0;
                const bf16x8 pa = __builtin_bit_cast(bf16x8, wv);
                #pragma unroll
                for (int n = 0; n < 4; ++n) {
                    const bf16x8 vb = *reinterpret_cast<const bf16x8*>(
                        &SM[AOFF_VT + (n * 16 + col) * ALDVT + c * 32 + g * 8]);
                    oacc[n] = mfma16(pa, vb, oacc[n]);
                }
            }
        }

        // store O (already normalized)
        #pragma unroll
        for (int n = 0; n < 4; ++n)
            #pragma unroll
            for (int r = 0; r < 4; ++r)
                out[((size_t)b * NT + MT * 16 + 4 * g + r) * NH + n * 16 + col] = oacc[n][r];
    }
}

// ============ fallback: round-1 fused kernel (known-correct) ===================
#define OFF_Q   0
#define LDQ     72
#define OFF_KF  18432
#define OFF_VTF 36864
#define LDVTF   264
#define OFF_WT  53760
#define LDWT    392
#define OFF_PWF 53760
#define LDPW    40
#define SMEM_U16 78848

__global__ __launch_bounds__(512, 2) void head_fused(
    const float* __restrict__ x, const float* __restrict__ Wq,
    const float* __restrict__ Wk, const float* __restrict__ Wv,
    float* __restrict__ out)
{
    __shared__ __align__(16) unsigned short SM[SMEM_U16];
    const int b = blockIdx.x, tid = threadIdx.x;
    const int w = tid >> 6, lane = tid & 63, g = lane >> 4, col = lane & 15;
    const int mt0 = w, mt1 = 15 - w;
    const f32x4 fzero = {0.f, 0.f, 0.f, 0.f};
    const float* xb = x + (size_t)b * NT * NC;

    bf16x8 xfrag[2][12];
    #pragma unroll
    for (int mt = 0; mt < 2; ++mt) {
        const int MTm = mt ? mt1 : mt0;
        const float* xrow = xb + (MTm * 16 + col) * NC;
        #pragma unroll
        for (int kk = 0; kk < 12; ++kk) {
            const float4 lo = *reinterpret_cast<const float4*>(xrow + kk * 32 + g * 8);
            const float4 hi = *reinterpret_cast<const float4*>(xrow + kk * 32 + g * 8 + 4);
            u16x8 u;
            u[0]=f2bf(lo.x);u[1]=f2bf(lo.y);u[2]=f2bf(lo.z);u[3]=f2bf(lo.w);
            u[4]=f2bf(hi.x);u[5]=f2bf(hi.y);u[6]=f2bf(hi.z);u[7]=f2bf(hi.w);
            xfrag[mt][kk] = __builtin_bit_cast(bf16x8, u);
        }
    }
    const float* Ws[3] = { Wq, Wk, Wv };
    #pragma unroll
    for (int pass = 0; pass < 3; ++pass) {
        const float* W = Ws[pass];
        for (int idx = tid; idx < NC * NH; idx += 512) {
            const int c = idx >> 6, h = idx & 63;
            SM[OFF_WT + h * LDWT + c] = f2bf(W[idx]);
        }
        __syncthreads();
        #pragma unroll
        for (int mt = 0; mt < 2; ++mt) {
            const int MTm = mt ? mt1 : mt0;
            f32x4 acc[4]; acc[0]=fzero;acc[1]=fzero;acc[2]=fzero;acc[3]=fzero;
            #pragma unroll
            for (int kk = 0; kk < 12; ++kk) {
                const bf16x8 a = xfrag[mt][kk];
                #pragma unroll
                for (int n = 0; n < 4; ++n) {
                    const bf16x8 bb = *reinterpret_cast<const bf16x8*>(
                        &SM[OFF_WT + (n * 16 + col) * LDWT + kk * 32 + g * 8]);
                    acc[n] = mfma16(a, bb, acc[n]);
                }
            }
            const int tb = MTm * 16 + g * 4;
            if (pass < 2) {
                const int base = (pass == 0) ? OFF_Q : OFF_KF;
                #pragma unroll
                for (int n = 0; n < 4; ++n)
                    #pragma unroll
                    for (int r = 0; r < 4; ++r)
                        SM[base + (tb + r) * LDQ + n * 16 + col] = f2bf(acc[n][r]);
            } else {
                #pragma unroll
                for (int n = 0; n < 4; ++n)
                    #pragma unroll
                    for (int r = 0; r < 4; ++r)
                        SM[OFF_VTF + (n * 16 + col) * LDVTF + tb + r] = f2bf(acc[n][r]);
            }
        }
        __syncthreads();
    }
    f32x4 sc[2][16];
    #pragma unroll
    for (int mt = 0; mt < 2; ++mt) {
        const int MTm = mt ? mt1 : mt0;
        bf16x8 qa[2];
        #pragma unroll
        for (int kk = 0; kk < 2; ++kk)
            qa[kk] = *reinterpret_cast<const bf16x8*>(
                &SM[OFF_Q + (MTm * 16 + col) * LDQ + kk * 32 + g * 8]);
        #pragma unroll
        for (int nt = 0; nt < 16; ++nt) {
            if (nt <= MTm) {
                f32x4 a = fzero;
                #pragma unroll
                for (int kk = 0; kk < 2; ++kk) {
                    const bf16x8 kb = *reinterpret_cast<const bf16x8*>(
                        &SM[OFF_KF + (nt * 16 + col) * LDQ + kk * 32 + g * 8]);
                    a = mfma16(qa[kk], kb, a);
                }
                sc[mt][nt] = a;
            }
        }
    }
    float inv_sum[2][4];
    #pragma unroll
    for (int mt = 0; mt < 2; ++mt) {
        const int MTm = mt ? mt1 : mt0;
        #pragma unroll
        for (int r = 0; r < 4; ++r) {
            float m = -INFINITY;
            #pragma unroll
            for (int nt = 0; nt < 16; ++nt) {
                if (nt <= MTm) {
                    float v = sc[mt][nt][r] * 0.125f;
                    if (nt == MTm && col > g * 4 + r) v = -INFINITY;
                    sc[mt][nt][r] = v;
                    m = fmaxf(m, v);
                }
            }
            m = fmaxf(m, __shfl_xor(m, 1)); m = fmaxf(m, __shfl_xor(m, 2));
            m = fmaxf(m, __shfl_xor(m, 4)); m = fmaxf(m, __shfl_xor(m, 8));
            float s = 0.f;
            #pragma unroll
            for (int nt = 0; nt < 16; ++nt) {
                if (nt <= MTm) {
                    const float p = __expf(sc[mt][nt][r] - m);
                    sc[mt][nt][r] = p; s += p;
                }
            }
            s += __shfl_xor(s, 1); s += __shfl_xor(s, 2);
            s += __shfl_xor(s, 4); s += __shfl_xor(s, 8);
            inv_sum[mt][r] = 1.0f / s;
        }
    }
    f32x4 oacc[2][4];
    #pragma unroll
    for (int mt = 0; mt < 2; ++mt)
        #pragma unroll
        for (int n = 0; n < 4; ++n) oacc[mt][n] = fzero;
    #pragma unroll
    for (int scn = 0; scn < 8; ++scn) {
        #pragma unroll
        for (int mt = 0; mt < 2; ++mt) {
            const int MTm = mt ? mt1 : mt0;
            if (2 * scn <= MTm) {
                #pragma unroll
                for (int half = 0; half < 2; ++half) {
                    const int nt = 2 * scn + half;
                    #pragma unroll
                    for (int r = 0; r < 4; ++r) {
                        float p = 0.f;
                        if (nt <= MTm) p = sc[mt][nt][r];
                        SM[OFF_PWF + ((w * 2 + mt) * 16 + g * 4 + r) * LDPW + half * 16 + col] = f2bf(p);
                    }
                }
            }
        }
        __syncthreads();
        #pragma unroll
        for (int mt = 0; mt < 2; ++mt) {
            const int MTm = mt ? mt1 : mt0;
            if (2 * scn <= MTm) {
                const bf16x8 pa = *reinterpret_cast<const bf16x8*>(
                    &SM[OFF_PWF + ((w * 2 + mt) * 16 + col) * LDPW + g * 8]);
                #pragma unroll
                for (int n = 0; n < 4; ++n) {
                    const bf16x8 vb = *reinterpret_cast<const bf16x8*>(
                        &SM[OFF_VTF + (n * 16 + col) * LDVTF + scn * 32 + g * 8]);
                    oacc[mt][n] = mfma16(pa, vb, oacc[mt][n]);
                }
            }
        }
        __syncthreads();
    }
    #pragma unroll
    for (int mt = 0; mt < 2; ++mt) {
        const int MTm = mt ? mt1 : mt0;
        #pragma unroll
        for (int n = 0; n < 4; ++n)
            #pragma unroll
            for (int r = 0; r < 4; ++r) {
                const int t = MTm * 16 + g * 4 + r;
                out[((size_t)b * NT + t) * NH + n * 16 + col] = oacc[mt][n][r] * inv_sum[mt][r];
            }
    }
}

// ============ launcher =========================================================
extern "C" void kernel_launch(void* const* d_in, const int* in_sizes, int n_in,
                              void* d_out, int out_size, void* d_ws, size_t ws_size,
                              hipStream_t stream) {
    (void)in_sizes; (void)n_in; (void)out_size;
    const float* x  = (const float*)d_in[0];
    const float* wq = (const float*)d_in[1];
    const float* wk = (const float*)d_in[2];
    const float* wv = (const float*)d_in[3];
    float* o = (float*)d_out;

    const size_t qkv_bytes = (size_t)NB * NT * NH * sizeof(unsigned short);  // 16 MiB
    const size_t need = 147456 + 3 * qkv_bytes;

    if (ws_size >= need) {
        unsigned short* Wf = (unsigned short*)d_ws;
        unsigned short* Qg = (unsigned short*)((char*)d_ws + 147456);
        unsigned short* Kg = (unsigned short*)((char*)Qg + qkv_bytes);
        unsigned short* VTg = (unsigned short*)((char*)Kg + qkv_bytes);
        prep_w  <<<dim3(288), dim3(256), 0, stream>>>(wq, wk, wv, Wf);
        proj_qkv<<<dim3(512), dim3(256), 0, stream>>>(x, Wf, Qg, Kg, VTg);
        attn    <<<dim3(NB),  dim3(512), 0, stream>>>(Qg, Kg, VTg, o);
    } else {
        head_fused<<<dim3(NB), dim3(512), 0, stream>>>(x, wq, wk, wv, o);
    }
}

// Round 6
// 74.431 us; speedup vs baseline: 2.0423x; 2.0423x over previous
//
#include <hip/hip_runtime.h>
#include <hip/hip_bf16.h>
#include <math.h>

#define NB 512
#define NT 256
#define NC 384
#define NH 64

typedef __bf16 bf16x8 __attribute__((ext_vector_type(8)));
typedef unsigned short u16x8 __attribute__((ext_vector_type(8)));
typedef unsigned short u16x4 __attribute__((ext_vector_type(4)));
typedef unsigned int   u32x4 __attribute__((ext_vector_type(4)));
typedef float f32x4 __attribute__((ext_vector_type(4)));

__device__ __forceinline__ unsigned short f2bf(float f) {
    union { float f; unsigned u; } v; v.f = f;
    unsigned r = v.u + 0x7FFFu + ((v.u >> 16) & 1u);   // round-to-nearest-even
    return (unsigned short)(r >> 16);
}

__device__ __forceinline__ f32x4 mfma16(bf16x8 a, bf16x8 b, f32x4 c) {
    return __builtin_amdgcn_mfma_f32_16x16x32_bf16(a, b, c, 0, 0, 0);
}

// ============ kernel 1: W -> Wf (bf16, MFMA B-fragment packed) =================
// Wf element e = ((n*12+kk)*64 + l)*8 + j  holds  W_m[c=kk*32+8*(l>>4)+j][h=(n&3)*16+(l&15)]
// (verified passing in rounds 4/5)
__global__ void prep_w(const float* __restrict__ Wq, const float* __restrict__ Wk,
                       const float* __restrict__ Wv, unsigned short* __restrict__ Wf) {
    const int e = blockIdx.x * 256 + threadIdx.x;   // 0..73727
    const int j  = e & 7;
    const int l  = (e >> 3) & 63;
    const int fi = e >> 9;                          // 0..143
    const int kk = fi % 12;
    const int n  = fi / 12;
    const int g = l >> 4, col = l & 15;
    const int c = kk * 32 + g * 8 + j;
    const int h = (n & 3) * 16 + col;
    const float* W = (n < 4) ? Wq : (n < 8 ? Wk : Wv);
    Wf[e] = f2bf(W[c * 64 + h]);
}

// ============ kernel 2: fully fused head ======================================
// One block per batch, 512 threads (8 waves). LDS regions (shorts):
//   Q  [256][72]   @ 0        (rows; read back as B-frags)
//   K  [256][72]   @ 18432
//   VT [64][264]   @ 36864    (V transposed)
//   XS [64][392]   @ 53760    (coalesced x staging, 4 chunks of 64 rows)
#define FOFF_Q   0
#define FLDQK    72
#define FOFF_K   18432
#define FOFF_VT  36864
#define FLDVT    264
#define FOFF_XS  53760
#define FLDXS    392
#define FSMEM    78848          // shorts = 157,696 B -> 1 block/CU

__global__ __launch_bounds__(512, 2) void head_v3(
    const float* __restrict__ x, const unsigned short* __restrict__ Wf,
    float* __restrict__ out)
{
    __shared__ __align__(16) unsigned short SM[FSMEM];

    const int b    = blockIdx.x;
    const int tid  = threadIdx.x;
    const int w    = tid >> 6;       // wave 0..7
    const int lane = tid & 63;
    const int g    = lane >> 4;
    const int col  = lane & 15;

    // ---------------- phase 1: coalesced x staging -> A-frags in regs --------
    // wave w owns row-tiles {w, 15-w} (balanced causal pairing)
    bf16x8 xfrag[2][12];
    #pragma unroll
    for (int ch = 0; ch < 4; ++ch) {
        const float* xb = x + ((size_t)b * NT + ch * 64) * NC;
        #pragma unroll
        for (int k = 0; k < 12; ++k) {
            const int idx = k * 2048 + tid * 4;     // 512 thr x 4 f32
            const int row = idx / 384;              // 0..63
            const int cc  = idx - row * 384;
            const float4 f = *reinterpret_cast<const float4*>(xb + idx);
            u16x4 u;
            u[0] = f2bf(f.x); u[1] = f2bf(f.y); u[2] = f2bf(f.z); u[3] = f2bf(f.w);
            *reinterpret_cast<u16x4*>(&SM[FOFF_XS + row * FLDXS + cc]) = u;
        }
        __syncthreads();
        #pragma unroll
        for (int mt = 0; mt < 2; ++mt) {
            const int MT = mt ? (15 - w) : w;
            if ((MT >> 2) == ch) {                  // wave-uniform
                const int lr = (MT & 3) * 16 + col; // local row in chunk
                #pragma unroll
                for (int kk = 0; kk < 12; ++kk)
                    xfrag[mt][kk] = *reinterpret_cast<const bf16x8*>(
                        &SM[FOFF_XS + lr * FLDXS + kk * 32 + g * 8]);
            }
        }
        __syncthreads();
    }

    // ---------------- phase 2: Q/K/V projection (B-frags from packed Wf) -----
    #pragma unroll
    for (int pass = 0; pass < 3; ++pass) {
        f32x4 acc[2][4];
        #pragma unroll
        for (int mt = 0; mt < 2; ++mt)
            #pragma unroll
            for (int n = 0; n < 4; ++n) acc[mt][n] = (f32x4){0.f, 0.f, 0.f, 0.f};
        #pragma unroll
        for (int kk = 0; kk < 12; ++kk) {
            bf16x8 bb[4];
            #pragma unroll
            for (int n = 0; n < 4; ++n)
                bb[n] = *reinterpret_cast<const bf16x8*>(
                    Wf + ((size_t)((pass * 4 + n) * 12 + kk) * 64 + lane) * 8);
            #pragma unroll
            for (int mt = 0; mt < 2; ++mt)
                #pragma unroll
                for (int n = 0; n < 4; ++n)
                    acc[mt][n] = mfma16(xfrag[mt][kk], bb[n], acc[mt][n]);
        }
        #pragma unroll
        for (int mt = 0; mt < 2; ++mt) {
            const int MT = mt ? (15 - w) : w;
            const int tb = MT * 16 + g * 4;
            if (pass < 2) {
                const int base = (pass == 0) ? FOFF_Q : FOFF_K;
                #pragma unroll
                for (int n = 0; n < 4; ++n)
                    #pragma unroll
                    for (int r = 0; r < 4; ++r)
                        SM[base + (tb + r) * FLDQK + n * 16 + col] = f2bf(acc[mt][n][r]);
            } else {
                #pragma unroll
                for (int n = 0; n < 4; ++n)
                    #pragma unroll
                    for (int r = 0; r < 4; ++r)
                        SM[FOFF_VT + (n * 16 + col) * FLDVT + tb + r] = f2bf(acc[mt][n][r]);
            }
        }
    }
    __syncthreads();   // Q/K/VT visible block-wide; no more barriers below

    // ---------------- phase 3: attention (swapped QK^T, shuffle PV) ----------
    const int hi_half = (lane >> 5) & 1;
    const int srcA = ((lane >> 4) & 1) * 32 + col;
    const int srcB = srcA + 16;

    #pragma unroll
    for (int pass = 0; pass < 2; ++pass) {
        const int MT = pass ? (15 - w) : w;

        // Q B-frags from LDS rows
        bf16x8 qb[2];
        #pragma unroll
        for (int kk = 0; kk < 2; ++kk)
            qb[kk] = *reinterpret_cast<const bf16x8*>(
                &SM[FOFF_Q + (MT * 16 + col) * FLDQK + kk * 32 + g * 8]);

        // scores S^T: lane holds S[s=nt*16+4g+r][t=MT*16+col]
        f32x4 sc[16];
        #pragma unroll
        for (int nt = 0; nt < 16; ++nt) {
            if (nt <= MT) {
                f32x4 a = {0.f, 0.f, 0.f, 0.f};
                const bf16x8 ka0 = *reinterpret_cast<const bf16x8*>(
                    &SM[FOFF_K + (nt * 16 + col) * FLDQK + g * 8]);
                const bf16x8 ka1 = *reinterpret_cast<const bf16x8*>(
                    &SM[FOFF_K + (nt * 16 + col) * FLDQK + 32 + g * 8]);
                a = mfma16(ka0, qb[0], a);
                a = mfma16(ka1, qb[1], a);
                sc[nt] = a;
            }
        }

        // softmax over s for row t=col; reduce across g with 2 shuffles
        float m = -INFINITY;
        #pragma unroll
        for (int nt = 0; nt < 16; ++nt) {
            if (nt <= MT) {
                #pragma unroll
                for (int r = 0; r < 4; ++r) {
                    float v = sc[nt][r] * 0.125f;
                    if (nt == MT && (4 * g + r) > col) v = -INFINITY;   // causal
                    sc[nt][r] = v;
                    m = fmaxf(m, v);
                }
            }
        }
        m = fmaxf(m, __shfl_xor(m, 16));
        m = fmaxf(m, __shfl_xor(m, 32));
        float s = 0.f;
        #pragma unroll
        for (int nt = 0; nt < 16; ++nt) {
            if (nt <= MT) {
                #pragma unroll
                for (int r = 0; r < 4; ++r) {
                    const float p = __expf(sc[nt][r] - m);
                    sc[nt][r] = p;
                    s += p;
                }
            }
        }
        s += __shfl_xor(s, 16);
        s += __shfl_xor(s, 32);
        const float inv = 1.0f / s;

        // normalized P -> bf16 pairs (per nt: r0|r1, r2|r3)
        unsigned P4lo[16], P4hi[16];
        #pragma unroll
        for (int nt = 0; nt < 16; ++nt) {
            if (nt <= MT) {
                P4lo[nt] = (unsigned)f2bf(sc[nt][0] * inv) |
                           ((unsigned)f2bf(sc[nt][1] * inv) << 16);
                P4hi[nt] = (unsigned)f2bf(sc[nt][2] * inv) |
                           ((unsigned)f2bf(sc[nt][3] * inv) << 16);
            } else { P4lo[nt] = 0u; P4hi[nt] = 0u; }
        }

        // PV: build P A-frags via shuffles (no LDS), accumulate O
        f32x4 oacc[4];
        #pragma unroll
        for (int n = 0; n < 4; ++n) oacc[n] = (f32x4){0.f, 0.f, 0.f, 0.f};
        #pragma unroll
        for (int cpv = 0; cpv < 8; ++cpv) {
            if (cpv <= (MT >> 1)) {
                const unsigned a0 = __shfl(P4lo[2 * cpv],     srcA, 64);
                const unsigned a1 = __shfl(P4lo[2 * cpv + 1], srcA, 64);
                const unsigned b0 = __shfl(P4hi[2 * cpv],     srcA, 64);
                const unsigned b1 = __shfl(P4hi[2 * cpv + 1], srcA, 64);
                const unsigned c0 = __shfl(P4lo[2 * cpv],     srcB, 64);
                const unsigned c1 = __shfl(P4lo[2 * cpv + 1], srcB, 64);
                const unsigned d0 = __shfl(P4hi[2 * cpv],     srcB, 64);
                const unsigned d1 = __shfl(P4hi[2 * cpv + 1], srcB, 64);
                u32x4 wv;
                wv[0] = hi_half ? a1 : a0;
                wv[1] = hi_half ? b1 : b0;
                wv[2] = hi_half ? c1 : c0;
                wv[3] = hi_half ? d1 : d0;
                const bf16x8 pa = __builtin_bit_cast(bf16x8, wv);
                #pragma unroll
                for (int n = 0; n < 4; ++n) {
                    const bf16x8 vb = *reinterpret_cast<const bf16x8*>(
                        &SM[FOFF_VT + (n * 16 + col) * FLDVT + cpv * 32 + g * 8]);
                    oacc[n] = mfma16(pa, vb, oacc[n]);
                }
            }
        }

        // store O (P already normalized)
        #pragma unroll
        for (int n = 0; n < 4; ++n)
            #pragma unroll
            for (int r = 0; r < 4; ++r)
                out[((size_t)b * NT + MT * 16 + 4 * g + r) * NH + n * 16 + col] = oacc[n][r];
    }
}

// ============ launcher =========================================================
extern "C" void kernel_launch(void* const* d_in, const int* in_sizes, int n_in,
                              void* d_out, int out_size, void* d_ws, size_t ws_size,
                              hipStream_t stream) {
    (void)in_sizes; (void)n_in; (void)out_size; (void)ws_size;
    const float* x  = (const float*)d_in[0];
    const float* wq = (const float*)d_in[1];
    const float* wk = (const float*)d_in[2];
    const float* wv = (const float*)d_in[3];
    float* o = (float*)d_out;

    unsigned short* Wf = (unsigned short*)d_ws;   // 147,456 B (ws is ~48 MB)
    prep_w <<<dim3(288), dim3(256), 0, stream>>>(wq, wk, wv, Wf);
    head_v3<<<dim3(NB),  dim3(512), 0, stream>>>(x, Wf, o);
}